// Round 1
// baseline (301.885 us; speedup 1.0000x reference)
//
#include <hip/hip_runtime.h>

// out[b,d] = sum_{j=0..x-1} hidden[b, start+j, d]
// start = clamp(sum(mask[B-1,:]) - x, 0, S-x)   (lax.dynamic_slice clamping)
//
// One thread per output float4 (gid over B*D4); window split jsplit ways over
// blockIdx.y so the 8 MB read spreads across all CUs. Partials combined with
// fp32 atomicAdd into memset-zeroed d_out. Each block redundantly reduces the
// last mask row (S int32, L2-hot) to get `start` without a separate kernel.
__global__ __launch_bounds__(256) void srs_window_sum(
    const float4* __restrict__ hidden,
    const int* __restrict__ mask,
    const int* __restrict__ xp,
    float* __restrict__ out,
    int B, int S, int D4, int jsplit)
{
    __shared__ int s_wave[4];
    __shared__ int s_start;
    const int tid = threadIdx.x;
    const int x = *xp;

    // --- per-block mask-row sum (row B-1) ---
    int acc = 0;
    const int* mrow = mask + (size_t)(B - 1) * S;
    for (int i = tid; i < S; i += 256) acc += mrow[i];
    #pragma unroll
    for (int off = 32; off > 0; off >>= 1) acc += __shfl_down(acc, off, 64);
    if ((tid & 63) == 0) s_wave[tid >> 6] = acc;
    __syncthreads();
    if (tid == 0) {
        int length = s_wave[0] + s_wave[1] + s_wave[2] + s_wave[3];
        int start = length - x;
        if (start < 0) start = 0;
        if (start > S - x) start = S - x;
        s_start = start;
    }
    __syncthreads();
    const int start = s_start;

    // --- windowed partial sum ---
    const int gid = blockIdx.x * 256 + tid;   // over B*D4
    if (gid >= B * D4) return;
    const int b = gid / D4;
    const int d = gid - b * D4;

    const int chunk = (x + jsplit - 1) / jsplit;
    const int j0 = blockIdx.y * chunk;
    int j1 = j0 + chunk; if (j1 > x) j1 = x;

    const float4* p = hidden + ((size_t)b * S + (size_t)start) * D4 + d;
    float4 s = make_float4(0.f, 0.f, 0.f, 0.f);
    for (int j = j0; j < j1; ++j) {
        float4 h = p[(size_t)j * D4];   // coalesced across threads (d contiguous)
        s.x += h.x; s.y += h.y; s.z += h.z; s.w += h.w;
    }

    float* o = out + (size_t)gid * 4;
    atomicAdd(o + 0, s.x);
    atomicAdd(o + 1, s.y);
    atomicAdd(o + 2, s.z);
    atomicAdd(o + 3, s.w);
}

extern "C" void kernel_launch(void* const* d_in, const int* in_sizes, int n_in,
                              void* d_out, int out_size, void* d_ws, size_t ws_size,
                              hipStream_t stream) {
    const float* hidden = (const float*)d_in[0];
    const int*   mask   = (const int*)d_in[1];
    const int*   xp     = (const int*)d_in[2];
    float*       out    = (float*)d_out;

    const long long nhid  = in_sizes[0];  // B*S*D
    const long long nmask = in_sizes[1];  // B*S
    const int D  = (int)(nhid / nmask);
    const int S  = (int)(nhid / (long long)out_size);  // (B*S*D)/(B*D)
    const int B  = out_size / D;
    const int D4 = D / 4;

    // d_out is poisoned 0xAA before every timed launch — zero it (capture-safe).
    hipMemsetAsync(d_out, 0, (size_t)out_size * sizeof(float), stream);

    const int jsplit = 8;
    dim3 grid((B * D4 + 255) / 256, jsplit);
    srs_window_sum<<<grid, 256, 0, stream>>>(
        (const float4*)hidden, mask, xp, out, B, S, D4, jsplit);
}